// Round 7
// baseline (361.027 us; speedup 1.0000x reference)
//
#include <hip/hip_runtime.h>
#include <hip/hip_fp16.h>

// GCNPredictor: 3-layer GCN (sum-aggregation) + sum-pool + MLP head.
// Round 7: 512-thread fused layer. 8 waves = (col-quarter q, edge-half h);
// node-per-lane gather with even/odd edge split -> 2x resident waves
// (toward 32 waves/CU) and half the serial edge chain per lane.
// fp16 inter-layer features (R6), fp32 accumulation everywhere.

constexpr int NUM_GRAPHS = 2048;

// ---------------- h0 = x @ W_emb  ([N,35] @ [35,8]) ----------------
__global__ __launch_bounds__(256) void k_embed(const float* __restrict__ x,
                                               const float* __restrict__ Wemb,
                                               float* __restrict__ h0, int N) {
  __shared__ float sx[32 * 35];
  __shared__ float sw[35 * 8];
  int n0 = blockIdx.x * 32;
  int cnt = min(32, N - n0);
  int nf = cnt * 35;
  for (int i = threadIdx.x; i < nf; i += 256) sx[i] = x[(size_t)n0 * 35 + i];
  for (int i = threadIdx.x; i < 35 * 8; i += 256) sw[i] = Wemb[i];
  __syncthreads();
  int nl = threadIdx.x >> 3;
  int c = threadIdx.x & 7;
  if (nl < cnt) {
    float acc = 0.f;
#pragma unroll
    for (int k = 0; k < 35; ++k) acc = fmaf(sx[nl * 35 + k], sw[k * 8 + c], acc);
    h0[(size_t)(n0 + nl) * 8 + c] = acc;
  }
}

// ---------------- CSR build: counts -> exclusive scan -> fill ----------------
__global__ __launch_bounds__(256) void k_hist(const int* __restrict__ dst,
                                              int* counts, int E) {
  int e = blockIdx.x * 256 + threadIdx.x;
  if (e < E) atomicAdd(&counts[dst[e]], 1);
}

__global__ __launch_bounds__(256) void k_scan1(const int* __restrict__ counts,
                                               int* __restrict__ offs,
                                               int* __restrict__ partials, int N) {
  __shared__ int s[256];
  int i = blockIdx.x * 256 + threadIdx.x;
  int v = (i < N) ? counts[i] : 0;
  s[threadIdx.x] = v;
  __syncthreads();
#pragma unroll
  for (int d = 1; d < 256; d <<= 1) {
    int t = (threadIdx.x >= d) ? s[threadIdx.x - d] : 0;
    __syncthreads();
    s[threadIdx.x] += t;
    __syncthreads();
  }
  if (i < N) offs[i] = s[threadIdx.x] - v;  // exclusive
  if (threadIdx.x == 255) partials[blockIdx.x] = s[255];
}

__global__ __launch_bounds__(512) void k_scan2(int* partials, int nb) {
  __shared__ int s[512];
  int t = threadIdx.x;
  int orig = (t < nb) ? partials[t] : 0;
  s[t] = orig;
  __syncthreads();
#pragma unroll
  for (int d = 1; d < 512; d <<= 1) {
    int v = (t >= d) ? s[t - d] : 0;
    __syncthreads();
    s[t] += v;
    __syncthreads();
  }
  if (t < nb) partials[t] = s[t] - orig;  // exclusive block offsets
}

__global__ __launch_bounds__(256) void k_scan3(int* __restrict__ offs,
                                               const int* __restrict__ partials,
                                               int* __restrict__ cursor, int N) {
  int i = blockIdx.x * 256 + threadIdx.x;
  if (i < N) {
    int v = offs[i] + partials[blockIdx.x];
    offs[i] = v;
    cursor[i] = v;
  }
}

__global__ __launch_bounds__(256) void k_fill(const int* __restrict__ src,
                                              const int* __restrict__ dst,
                                              int* cursor, int* __restrict__ csr,
                                              int E) {
  int e = blockIdx.x * 256 + threadIdx.x;
  if (e < E) {
    int slot = atomicAdd(&cursor[dst[e]], 1);
    csr[slot] = src[e];
  }
}

// -------- layer 0 fused: agg8 = gather(h0); out = relu(agg8 @ W_g0), fp16 out
__global__ __launch_bounds__(256) void k_layer0(const float* __restrict__ h0,
                                                const int* __restrict__ csr,
                                                const int* __restrict__ offs,
                                                const int* __restrict__ cnts,
                                                const float* __restrict__ W,
                                                __half* __restrict__ out, int N) {
  __shared__ float sagg[32 * 9];  // stride 9: conflict-free
  __shared__ float sw[8 * 128];
  for (int i = threadIdx.x; i < 1024; i += 256) sw[i] = W[i];
  int n0 = blockIdx.x * 32;
  {
    int i = threadIdx.x >> 3;
    int c = threadIdx.x & 7;
    int n = n0 + i;
    float acc = 0.f;
    if (n < N) {
      int s = offs[n], cc = cnts[n];
      for (int e = 0; e < cc; ++e) acc += h0[(size_t)csr[s + e] * 8 + c];
    }
    sagg[i * 9 + c] = acc;
  }
  __syncthreads();
  int i2 = threadIdx.x >> 3;
  int j0 = (threadIdx.x & 7) * 16;
  int n2 = n0 + i2;
  if (n2 >= N) return;
  float a[8];
#pragma unroll
  for (int k = 0; k < 8; ++k) a[k] = sagg[i2 * 9 + k];
  float og[16];
#pragma unroll
  for (int j = 0; j < 16; ++j) og[j] = 0.f;
#pragma unroll
  for (int k = 0; k < 8; ++k)
#pragma unroll
    for (int j = 0; j < 16; ++j) og[j] = fmaf(a[k], sw[k * 128 + j0 + j], og[j]);
  size_t base = (size_t)n2 * 128 + j0;
  __half2 o[8];
#pragma unroll
  for (int t4 = 0; t4 < 8; ++t4)
    o[t4] = __floats2half2_rn(fmaxf(og[2 * t4], 0.f), fmaxf(og[2 * t4 + 1], 0.f));
  *reinterpret_cast<float4*>(out + base) = *reinterpret_cast<float4*>(&o[0]);
  *reinterpret_cast<float4*>(out + base + 8) = *reinterpret_cast<float4*>(&o[4]);
}

// accumulate 8 halves (one float4 worth) into two float4 accumulators
__device__ __forceinline__ void acc_half8(float4& a0, float4& a1, float4 v) {
  const __half2* p = reinterpret_cast<const __half2*>(&v);
  float2 f0 = __half22float2(p[0]);
  float2 f1 = __half22float2(p[1]);
  float2 f2 = __half22float2(p[2]);
  float2 f3 = __half22float2(p[3]);
  a0.x += f0.x; a0.y += f0.y; a0.z += f1.x; a0.w += f1.y;
  a1.x += f2.x; a1.y += f2.y; a1.z += f3.x; a1.w += f3.y;
}

// -------- fused GCN layer (d=128, fp16 H): agg = gather(H); v = relu(agg@W)+H
// 512 threads = 8 waves: wave = (q = w&3 col-quarter, h = w>>2 edge-half).
// Lane l owns node n0+l; stream h takes edges h, h+2, h+4, ... of that node.
// Partials combine via two-phase LDS write/add. fp32 accumulation.
// mode 0: out[n] = v (fp16). mode 1: G[gid[n]] += v (pool fused, fp32 G).
__global__ __launch_bounds__(512, 8) void k_gcn_fused(
    const __half* __restrict__ H, const int* __restrict__ csr,
    const int* __restrict__ offs, const int* __restrict__ cnts,
    const float* __restrict__ W, __half* __restrict__ out,
    float* G, const int* __restrict__ gid, int N, int mode) {
  __shared__ float sa[64 * 132];
  int n0 = blockIdx.x * 64;

  // gather phase
  {
    int w = threadIdx.x >> 6;  // 0..7
    int q = w & 3;             // column quarter
    int h = w >> 2;            // edge half (even/odd)
    int l = threadIdx.x & 63;  // node lane
    int n = n0 + l;
    float4 acc[8];
#pragma unroll
    for (int i = 0; i < 8; ++i) acc[i] = make_float4(0.f, 0.f, 0.f, 0.f);
    int cnt = (n < N) ? cnts[n] : 0;
    int s = (n < N) ? offs[n] : 0;
    const __half* Hq = H + q * 32;
    int e = h;
    for (; e + 2 < cnt; e += 4) {  // two stride-2 edges per iter
      int s0 = csr[s + e], s1 = csr[s + e + 2];
      const float4* r0 = reinterpret_cast<const float4*>(Hq + (size_t)s0 * 128);
      const float4* r1 = reinterpret_cast<const float4*>(Hq + (size_t)s1 * 128);
      float4 a0 = r0[0], a1 = r0[1], a2 = r0[2], a3 = r0[3];
      float4 b0 = r1[0], b1 = r1[1], b2 = r1[2], b3 = r1[3];
      acc_half8(acc[0], acc[1], a0);
      acc_half8(acc[2], acc[3], a1);
      acc_half8(acc[4], acc[5], a2);
      acc_half8(acc[6], acc[7], a3);
      acc_half8(acc[0], acc[1], b0);
      acc_half8(acc[2], acc[3], b1);
      acc_half8(acc[4], acc[5], b2);
      acc_half8(acc[6], acc[7], b3);
    }
    if (e < cnt) {
      int s0 = csr[s + e];
      const float4* r0 = reinterpret_cast<const float4*>(Hq + (size_t)s0 * 128);
      float4 a0 = r0[0], a1 = r0[1], a2 = r0[2], a3 = r0[3];
      acc_half8(acc[0], acc[1], a0);
      acc_half8(acc[2], acc[3], a1);
      acc_half8(acc[4], acc[5], a2);
      acc_half8(acc[6], acc[7], a3);
    }
    float* srow = &sa[l * 132 + q * 32];
    if (h == 0) {
#pragma unroll
      for (int i = 0; i < 8; ++i)
        *reinterpret_cast<float4*>(srow + 4 * i) = acc[i];
    }
    __syncthreads();
    if (h == 1) {
#pragma unroll
      for (int i = 0; i < 8; ++i) {
        float4 t = *reinterpret_cast<const float4*>(srow + 4 * i);
        t.x += acc[i].x; t.y += acc[i].y; t.z += acc[i].z; t.w += acc[i].w;
        *reinterpret_cast<float4*>(srow + 4 * i) = t;
      }
    }
  }
  __syncthreads();

  // GEMM 64x128 @ 128x128 (fp32): 32 row-threads x 16 col-threads
  int nl = threadIdx.x >> 4;        // 0..31
  int j0 = (threadIdx.x & 15) * 8;  // 0..120
  float acc[2][8];
#pragma unroll
  for (int r = 0; r < 2; ++r)
#pragma unroll
    for (int j = 0; j < 8; ++j) acc[r][j] = 0.f;
  const float* Wj = W + j0;
#pragma unroll 2
  for (int k = 0; k < 128; ++k) {
    float4 w0 = *reinterpret_cast<const float4*>(Wj + (size_t)k * 128);
    float4 w1 = *reinterpret_cast<const float4*>(Wj + (size_t)k * 128 + 4);
    float wv[8] = {w0.x, w0.y, w0.z, w0.w, w1.x, w1.y, w1.z, w1.w};
#pragma unroll
    for (int r = 0; r < 2; ++r) {
      float a = sa[(nl + 32 * r) * 132 + k];
#pragma unroll
      for (int j = 0; j < 8; ++j) acc[r][j] = fmaf(a, wv[j], acc[r][j]);
    }
  }

  if (mode == 0) {
#pragma unroll
    for (int r = 0; r < 2; ++r) {
      int row = nl + 32 * r;
      int n = n0 + row;
      if (n < N) {
        size_t base = (size_t)n * 128 + j0;
        float4 hv = *reinterpret_cast<const float4*>(H + base);
        const __half2* hp = reinterpret_cast<const __half2*>(&hv);
        float2 f0 = __half22float2(hp[0]);
        float2 f1 = __half22float2(hp[1]);
        float2 f2 = __half22float2(hp[2]);
        float2 f3 = __half22float2(hp[3]);
        __half2 ov[4];
        ov[0] = __floats2half2_rn(fmaxf(acc[r][0], 0.f) + f0.x,
                                  fmaxf(acc[r][1], 0.f) + f0.y);
        ov[1] = __floats2half2_rn(fmaxf(acc[r][2], 0.f) + f1.x,
                                  fmaxf(acc[r][3], 0.f) + f1.y);
        ov[2] = __floats2half2_rn(fmaxf(acc[r][4], 0.f) + f2.x,
                                  fmaxf(acc[r][5], 0.f) + f2.y);
        ov[3] = __floats2half2_rn(fmaxf(acc[r][6], 0.f) + f3.x,
                                  fmaxf(acc[r][7], 0.f) + f3.y);
        *reinterpret_cast<float4*>(out + base) = *reinterpret_cast<float4*>(ov);
      }
    }
  } else {
    __syncthreads();  // all GEMM reads of sa done
#pragma unroll
    for (int r = 0; r < 2; ++r) {
      int row = nl + 32 * r;
      int n = n0 + row;
      if (n < N) {
        size_t base = (size_t)n * 128 + j0;
        float4 hv = *reinterpret_cast<const float4*>(H + base);
        const __half2* hp = reinterpret_cast<const __half2*>(&hv);
        float2 f0 = __half22float2(hp[0]);
        float2 f1 = __half22float2(hp[1]);
        float2 f2 = __half22float2(hp[2]);
        float2 f3 = __half22float2(hp[3]);
        float* srow = &sa[row * 132 + j0];
        srow[0] = fmaxf(acc[r][0], 0.f) + f0.x;
        srow[1] = fmaxf(acc[r][1], 0.f) + f0.y;
        srow[2] = fmaxf(acc[r][2], 0.f) + f1.x;
        srow[3] = fmaxf(acc[r][3], 0.f) + f1.y;
        srow[4] = fmaxf(acc[r][4], 0.f) + f2.x;
        srow[5] = fmaxf(acc[r][5], 0.f) + f2.y;
        srow[6] = fmaxf(acc[r][6], 0.f) + f3.x;
        srow[7] = fmaxf(acc[r][7], 0.f) + f3.y;
      }
    }
    __syncthreads();
    int grp = threadIdx.x >> 7;  // 0..3 -> rows [16*grp, 16*grp+16)
    int j = threadIdx.x & 127;
    int r0 = grp * 16;
    int nfirst = n0 + r0;
    if (nfirst < N) {
      float pacc = 0.f;
      int cur = gid[nfirst];
      for (int r = r0; r < r0 + 16; ++r) {
        int n = n0 + r;
        if (n >= N) break;
        int g2 = gid[n];
        if (g2 != cur) {
          atomicAdd(&G[(size_t)cur * 128 + j], pacc);
          pacc = 0.f;
          cur = g2;
        }
        pacc += sa[r * 132 + j];
      }
      atomicAdd(&G[(size_t)cur * 128 + j], pacc);
    }
  }
}

// ---------------- pred = relu(g @ W_p1) @ W_p2 + b ----------------
__global__ __launch_bounds__(64) void k_head(const float* __restrict__ g,
                                             const float* __restrict__ W1,
                                             const float* __restrict__ W2,
                                             const float* __restrict__ b,
                                             float* __restrict__ out) {
  int gi = blockIdx.x;
  int j = threadIdx.x;
  __shared__ float sg[128];
  sg[j] = g[(size_t)gi * 128 + j];
  sg[j + 64] = g[(size_t)gi * 128 + 64 + j];
  __syncthreads();
  float acc = 0.f;
#pragma unroll
  for (int k = 0; k < 128; ++k) acc = fmaf(sg[k], W1[k * 64 + j], acc);
  acc = fmaxf(acc, 0.f) * W2[j];
#pragma unroll
  for (int off = 32; off > 0; off >>= 1) acc += __shfl_down(acc, off);
  if (j == 0) out[gi] = acc + b[0];
}

extern "C" void kernel_launch(void* const* d_in, const int* in_sizes, int n_in,
                              void* d_out, int out_size, void* d_ws, size_t ws_size,
                              hipStream_t stream) {
  const float* x    = (const float*)d_in[0];
  const float* Wemb = (const float*)d_in[1];
  const float* Wg0  = (const float*)d_in[2];
  const float* Wg1  = (const float*)d_in[3];
  const float* Wg2  = (const float*)d_in[4];
  const float* Wp1  = (const float*)d_in[5];
  const float* Wp2  = (const float*)d_in[6];
  const float* bp2  = (const float*)d_in[7];
  const int* esrc   = (const int*)d_in[8];
  const int* edst   = (const int*)d_in[9];
  const int* gids   = (const int*)d_in[10];
  int N = in_sizes[0] / 35;
  int E = in_sizes[8];
  float* out = (float*)d_out;

  // workspace layout (bytes)
  char* wp = (char*)d_ws;
  float* h0 = (float*)wp;            wp += (size_t)N * 8 * sizeof(float);
  __half* P = (__half*)wp;           wp += (size_t)N * 128 * sizeof(__half);
  __half* Q = (__half*)wp;           wp += (size_t)N * 128 * sizeof(__half);
  float* G  = (float*)wp;            wp += (size_t)NUM_GRAPHS * 128 * sizeof(float);
  int* counts   = (int*)wp;          wp += (size_t)N * sizeof(int);
  int* offs     = (int*)wp;          wp += (size_t)N * sizeof(int);
  int* cursor   = (int*)wp;          wp += (size_t)N * sizeof(int);
  int* partials = (int*)wp;          wp += 512 * sizeof(int);
  int* csr      = (int*)wp;

  int nbE = (E + 255) / 256;
  int nbN = (N + 255) / 256;

  // embed (independent)
  k_embed<<<(N + 31) / 32, 256, 0, stream>>>(x, Wemb, h0, N);

  // CSR build
  hipMemsetAsync(counts, 0, (size_t)N * sizeof(int), stream);
  k_hist<<<nbE, 256, 0, stream>>>(edst, counts, E);
  k_scan1<<<nbN, 256, 0, stream>>>(counts, offs, partials, N);
  k_scan2<<<1, 512, 0, stream>>>(partials, nbN);
  k_scan3<<<nbN, 256, 0, stream>>>(offs, partials, cursor, N);
  k_fill<<<nbE, 256, 0, stream>>>(esrc, edst, cursor, csr, E);

  // zero pooled output (layer-2 epilogue atomics accumulate into it)
  hipMemsetAsync(G, 0, (size_t)NUM_GRAPHS * 128 * sizeof(float), stream);

  // layer 0: P = relu(gather(h0) @ W_g0)   (fp16 out)
  k_layer0<<<(N + 31) / 32, 256, 0, stream>>>(h0, csr, offs, counts, Wg0, P, N);

  // layer 1: Q = relu(gather(P) @ W_g1) + P
  k_gcn_fused<<<(N + 63) / 64, 512, 0, stream>>>(P, csr, offs, counts, Wg1, Q,
                                                 nullptr, nullptr, N, 0);

  // layer 2 + pool: G[gid] += relu(gather(Q) @ W_g2) + Q
  k_gcn_fused<<<(N + 63) / 64, 512, 0, stream>>>(Q, csr, offs, counts, Wg2, nullptr,
                                                 G, gids, N, 1);

  // head
  k_head<<<NUM_GRAPHS, 64, 0, stream>>>(G, Wp1, Wp2, bp2, out);
}

// Round 8
// 250.825 us; speedup vs baseline: 1.4394x; 1.4394x over previous
//
#include <hip/hip_runtime.h>
#include <hip/hip_fp16.h>

// GCNPredictor: 3-layer GCN (sum-aggregation) + sum-pool + MLP head.
// Round 8: R6 structure (256-thread fused layer, fp16 features — best
// measured) + LDS-staged CSR slice (removes the ~200cyc csr load from the
// per-edge dependent chain; staged into the sa buffer, zero extra LDS)
// + 4-edge unrolled gather (4 independent 64B lines in flight per lane).

constexpr int NUM_GRAPHS = 2048;

// ---------------- h0 = x @ W_emb  ([N,35] @ [35,8]) ----------------
__global__ __launch_bounds__(256) void k_embed(const float* __restrict__ x,
                                               const float* __restrict__ Wemb,
                                               float* __restrict__ h0, int N) {
  __shared__ float sx[32 * 35];
  __shared__ float sw[35 * 8];
  int n0 = blockIdx.x * 32;
  int cnt = min(32, N - n0);
  int nf = cnt * 35;
  for (int i = threadIdx.x; i < nf; i += 256) sx[i] = x[(size_t)n0 * 35 + i];
  for (int i = threadIdx.x; i < 35 * 8; i += 256) sw[i] = Wemb[i];
  __syncthreads();
  int nl = threadIdx.x >> 3;
  int c = threadIdx.x & 7;
  if (nl < cnt) {
    float acc = 0.f;
#pragma unroll
    for (int k = 0; k < 35; ++k) acc = fmaf(sx[nl * 35 + k], sw[k * 8 + c], acc);
    h0[(size_t)(n0 + nl) * 8 + c] = acc;
  }
}

// ---------------- CSR build: counts -> exclusive scan -> fill ----------------
__global__ __launch_bounds__(256) void k_hist(const int* __restrict__ dst,
                                              int* counts, int E) {
  int e = blockIdx.x * 256 + threadIdx.x;
  if (e < E) atomicAdd(&counts[dst[e]], 1);
}

__global__ __launch_bounds__(256) void k_scan1(const int* __restrict__ counts,
                                               int* __restrict__ offs,
                                               int* __restrict__ partials, int N) {
  __shared__ int s[256];
  int i = blockIdx.x * 256 + threadIdx.x;
  int v = (i < N) ? counts[i] : 0;
  s[threadIdx.x] = v;
  __syncthreads();
#pragma unroll
  for (int d = 1; d < 256; d <<= 1) {
    int t = (threadIdx.x >= d) ? s[threadIdx.x - d] : 0;
    __syncthreads();
    s[threadIdx.x] += t;
    __syncthreads();
  }
  if (i < N) offs[i] = s[threadIdx.x] - v;  // exclusive
  if (threadIdx.x == 255) partials[blockIdx.x] = s[255];
}

__global__ __launch_bounds__(512) void k_scan2(int* partials, int nb) {
  __shared__ int s[512];
  int t = threadIdx.x;
  int orig = (t < nb) ? partials[t] : 0;
  s[t] = orig;
  __syncthreads();
#pragma unroll
  for (int d = 1; d < 512; d <<= 1) {
    int v = (t >= d) ? s[t - d] : 0;
    __syncthreads();
    s[t] += v;
    __syncthreads();
  }
  if (t < nb) partials[t] = s[t] - orig;  // exclusive block offsets
}

__global__ __launch_bounds__(256) void k_scan3(int* __restrict__ offs,
                                               const int* __restrict__ partials,
                                               int* __restrict__ cursor, int N) {
  int i = blockIdx.x * 256 + threadIdx.x;
  if (i < N) {
    int v = offs[i] + partials[blockIdx.x];
    offs[i] = v;
    cursor[i] = v;
  }
}

__global__ __launch_bounds__(256) void k_fill(const int* __restrict__ src,
                                              const int* __restrict__ dst,
                                              int* cursor, int* __restrict__ csr,
                                              int E) {
  int e = blockIdx.x * 256 + threadIdx.x;
  if (e < E) {
    int slot = atomicAdd(&cursor[dst[e]], 1);
    csr[slot] = src[e];
  }
}

// -------- layer 0 fused: agg8 = gather(h0); out = relu(agg8 @ W_g0), fp16 out
__global__ __launch_bounds__(256) void k_layer0(const float* __restrict__ h0,
                                                const int* __restrict__ csr,
                                                const int* __restrict__ offs,
                                                const int* __restrict__ cnts,
                                                const float* __restrict__ W,
                                                __half* __restrict__ out, int N) {
  __shared__ float sagg[32 * 9];  // stride 9: conflict-free
  __shared__ float sw[8 * 128];
  for (int i = threadIdx.x; i < 1024; i += 256) sw[i] = W[i];
  int n0 = blockIdx.x * 32;
  {
    int i = threadIdx.x >> 3;
    int c = threadIdx.x & 7;
    int n = n0 + i;
    float acc = 0.f;
    if (n < N) {
      int s = offs[n], cc = cnts[n];
      for (int e = 0; e < cc; ++e) acc += h0[(size_t)csr[s + e] * 8 + c];
    }
    sagg[i * 9 + c] = acc;
  }
  __syncthreads();
  int i2 = threadIdx.x >> 3;
  int j0 = (threadIdx.x & 7) * 16;
  int n2 = n0 + i2;
  if (n2 >= N) return;
  float a[8];
#pragma unroll
  for (int k = 0; k < 8; ++k) a[k] = sagg[i2 * 9 + k];
  float og[16];
#pragma unroll
  for (int j = 0; j < 16; ++j) og[j] = 0.f;
#pragma unroll
  for (int k = 0; k < 8; ++k)
#pragma unroll
    for (int j = 0; j < 16; ++j) og[j] = fmaf(a[k], sw[k * 128 + j0 + j], og[j]);
  size_t base = (size_t)n2 * 128 + j0;
  __half2 o[8];
#pragma unroll
  for (int t4 = 0; t4 < 8; ++t4)
    o[t4] = __floats2half2_rn(fmaxf(og[2 * t4], 0.f), fmaxf(og[2 * t4 + 1], 0.f));
  *reinterpret_cast<float4*>(out + base) = *reinterpret_cast<float4*>(&o[0]);
  *reinterpret_cast<float4*>(out + base + 8) = *reinterpret_cast<float4*>(&o[4]);
}

// accumulate 8 halves (one float4 worth) into two float4 accumulators
__device__ __forceinline__ void acc_half8(float4& a0, float4& a1, float4 v) {
  const __half2* p = reinterpret_cast<const __half2*>(&v);
  float2 f0 = __half22float2(p[0]);
  float2 f1 = __half22float2(p[1]);
  float2 f2 = __half22float2(p[2]);
  float2 f3 = __half22float2(p[3]);
  a0.x += f0.x; a0.y += f0.y; a0.z += f1.x; a0.w += f1.y;
  a1.x += f2.x; a1.y += f2.y; a1.z += f3.x; a1.w += f3.y;
}

// -------- fused GCN layer (d=128, fp16 H): agg = gather(H); v = relu(agg@W)+H
// Gather: wave q (of 4) owns cols [32q,32q+32); lane l owns node n0+l.
// CSR slice for the block staged in LDS (aliased into sa), 4-edge unroll.
// mode 0: out[n] = v (fp16). mode 1: G[gid[n]] += v (pool fused, fp32 G).
__global__ __launch_bounds__(256) void k_gcn_fused(
    const __half* __restrict__ H, const int* __restrict__ csr,
    const int* __restrict__ offs, const int* __restrict__ cnts,
    const float* __restrict__ W, __half* __restrict__ out,
    float* G, const int* __restrict__ gid, int N, int E, int mode) {
  __shared__ float sa[64 * 132];
  int* sidx = reinterpret_cast<int*>(sa);  // aliased: CSR slice during gather
  int n0 = blockIdx.x * 64;

  int e0 = offs[n0];
  int e1 = (n0 + 64 < N) ? offs[n0 + 64] : E;
  int nedge = e1 - e0;
  bool staged = (nedge <= 64 * 132);

  // stage CSR slice into LDS (coalesced)
  if (staged) {
    for (int i = threadIdx.x; i < nedge; i += 256) sidx[i] = csr[e0 + i];
  }
  __syncthreads();

  // gather phase: acc in registers
  int q = threadIdx.x >> 6;  // column quarter
  int l = threadIdx.x & 63;  // node lane
  {
    int n = n0 + l;
    float4 acc[8];
#pragma unroll
    for (int i = 0; i < 8; ++i) acc[i] = make_float4(0.f, 0.f, 0.f, 0.f);
    int cnt = (n < N) ? cnts[n] : 0;
    int sb = (n < N) ? (offs[n] - e0) : 0;
    const __half* Hq = H + q * 32;
    if (staged) {
      int e = 0;
      for (; e + 4 <= cnt; e += 4) {
        int s0 = sidx[sb + e], s1 = sidx[sb + e + 1];
        int s2 = sidx[sb + e + 2], s3 = sidx[sb + e + 3];
        const float4* r0 = reinterpret_cast<const float4*>(Hq + (size_t)s0 * 128);
        const float4* r1 = reinterpret_cast<const float4*>(Hq + (size_t)s1 * 128);
        const float4* r2 = reinterpret_cast<const float4*>(Hq + (size_t)s2 * 128);
        const float4* r3 = reinterpret_cast<const float4*>(Hq + (size_t)s3 * 128);
        float4 a0 = r0[0], a1 = r0[1], a2 = r0[2], a3 = r0[3];
        float4 b0 = r1[0], b1 = r1[1], b2 = r1[2], b3 = r1[3];
        float4 c0 = r2[0], c1 = r2[1], c2 = r2[2], c3 = r2[3];
        float4 d0 = r3[0], d1 = r3[1], d2 = r3[2], d3 = r3[3];
        acc_half8(acc[0], acc[1], a0);
        acc_half8(acc[2], acc[3], a1);
        acc_half8(acc[4], acc[5], a2);
        acc_half8(acc[6], acc[7], a3);
        acc_half8(acc[0], acc[1], b0);
        acc_half8(acc[2], acc[3], b1);
        acc_half8(acc[4], acc[5], b2);
        acc_half8(acc[6], acc[7], b3);
        acc_half8(acc[0], acc[1], c0);
        acc_half8(acc[2], acc[3], c1);
        acc_half8(acc[4], acc[5], c2);
        acc_half8(acc[6], acc[7], c3);
        acc_half8(acc[0], acc[1], d0);
        acc_half8(acc[2], acc[3], d1);
        acc_half8(acc[4], acc[5], d2);
        acc_half8(acc[6], acc[7], d3);
      }
      for (; e < cnt; ++e) {
        int s0 = sidx[sb + e];
        const float4* r0 = reinterpret_cast<const float4*>(Hq + (size_t)s0 * 128);
        float4 a0 = r0[0], a1 = r0[1], a2 = r0[2], a3 = r0[3];
        acc_half8(acc[0], acc[1], a0);
        acc_half8(acc[2], acc[3], a1);
        acc_half8(acc[4], acc[5], a2);
        acc_half8(acc[6], acc[7], a3);
      }
    } else {
      // fallback: read csr from global (astronomically unlikely)
      int s = (n < N) ? offs[n] : 0;
      for (int e = 0; e < cnt; ++e) {
        int s0 = csr[s + e];
        const float4* r0 = reinterpret_cast<const float4*>(Hq + (size_t)s0 * 128);
        float4 a0 = r0[0], a1 = r0[1], a2 = r0[2], a3 = r0[3];
        acc_half8(acc[0], acc[1], a0);
        acc_half8(acc[2], acc[3], a1);
        acc_half8(acc[4], acc[5], a2);
        acc_half8(acc[6], acc[7], a3);
      }
    }
    __syncthreads();  // all sidx reads done; sa can be overwritten
    float* srow = &sa[l * 132 + q * 32];
#pragma unroll
    for (int i = 0; i < 8; ++i)
      *reinterpret_cast<float4*>(srow + 4 * i) = acc[i];
  }
  __syncthreads();

  // GEMM 64x128 @ 128x128 (fp32)
  int nl = threadIdx.x >> 4;
  int j0 = (threadIdx.x & 15) * 8;
  float acc[4][8];
#pragma unroll
  for (int r = 0; r < 4; ++r)
#pragma unroll
    for (int j = 0; j < 8; ++j) acc[r][j] = 0.f;
  const float* Wj = W + j0;
#pragma unroll 2
  for (int k = 0; k < 128; ++k) {
    float4 w0 = *reinterpret_cast<const float4*>(Wj + (size_t)k * 128);
    float4 w1 = *reinterpret_cast<const float4*>(Wj + (size_t)k * 128 + 4);
    float wv[8] = {w0.x, w0.y, w0.z, w0.w, w1.x, w1.y, w1.z, w1.w};
#pragma unroll
    for (int r = 0; r < 4; ++r) {
      float a = sa[(nl + 16 * r) * 132 + k];
#pragma unroll
      for (int j = 0; j < 8; ++j) acc[r][j] = fmaf(a, wv[j], acc[r][j]);
    }
  }

  if (mode == 0) {
#pragma unroll
    for (int r = 0; r < 4; ++r) {
      int row = nl + 16 * r;
      int n = n0 + row;
      if (n < N) {
        size_t base = (size_t)n * 128 + j0;
        float4 hv = *reinterpret_cast<const float4*>(H + base);
        const __half2* hp = reinterpret_cast<const __half2*>(&hv);
        float2 f0 = __half22float2(hp[0]);
        float2 f1 = __half22float2(hp[1]);
        float2 f2 = __half22float2(hp[2]);
        float2 f3 = __half22float2(hp[3]);
        __half2 ov[4];
        ov[0] = __floats2half2_rn(fmaxf(acc[r][0], 0.f) + f0.x,
                                  fmaxf(acc[r][1], 0.f) + f0.y);
        ov[1] = __floats2half2_rn(fmaxf(acc[r][2], 0.f) + f1.x,
                                  fmaxf(acc[r][3], 0.f) + f1.y);
        ov[2] = __floats2half2_rn(fmaxf(acc[r][4], 0.f) + f2.x,
                                  fmaxf(acc[r][5], 0.f) + f2.y);
        ov[3] = __floats2half2_rn(fmaxf(acc[r][6], 0.f) + f3.x,
                                  fmaxf(acc[r][7], 0.f) + f3.y);
        *reinterpret_cast<float4*>(out + base) = *reinterpret_cast<float4*>(ov);
      }
    }
  } else {
    __syncthreads();  // all GEMM reads of sa done
#pragma unroll
    for (int r = 0; r < 4; ++r) {
      int row = nl + 16 * r;
      int n = n0 + row;
      if (n < N) {
        size_t base = (size_t)n * 128 + j0;
        float4 hv = *reinterpret_cast<const float4*>(H + base);
        const __half2* hp = reinterpret_cast<const __half2*>(&hv);
        float2 f0 = __half22float2(hp[0]);
        float2 f1 = __half22float2(hp[1]);
        float2 f2 = __half22float2(hp[2]);
        float2 f3 = __half22float2(hp[3]);
        float* srow = &sa[row * 132 + j0];
        srow[0] = fmaxf(acc[r][0], 0.f) + f0.x;
        srow[1] = fmaxf(acc[r][1], 0.f) + f0.y;
        srow[2] = fmaxf(acc[r][2], 0.f) + f1.x;
        srow[3] = fmaxf(acc[r][3], 0.f) + f1.y;
        srow[4] = fmaxf(acc[r][4], 0.f) + f2.x;
        srow[5] = fmaxf(acc[r][5], 0.f) + f2.y;
        srow[6] = fmaxf(acc[r][6], 0.f) + f3.x;
        srow[7] = fmaxf(acc[r][7], 0.f) + f3.y;
      }
    }
    __syncthreads();
    int grp = threadIdx.x >> 7;  // 0..1 -> rows [0,32) / [32,64)
    int j = threadIdx.x & 127;
    int r0 = grp * 32;
    int nfirst = n0 + r0;
    if (nfirst < N) {
      float pacc = 0.f;
      int cur = gid[nfirst];
      for (int r = r0; r < r0 + 32; ++r) {
        int n = n0 + r;
        if (n >= N) break;
        int g2 = gid[n];
        if (g2 != cur) {
          atomicAdd(&G[(size_t)cur * 128 + j], pacc);
          pacc = 0.f;
          cur = g2;
        }
        pacc += sa[r * 132 + j];
      }
      atomicAdd(&G[(size_t)cur * 128 + j], pacc);
    }
  }
}

// ---------------- pred = relu(g @ W_p1) @ W_p2 + b ----------------
__global__ __launch_bounds__(64) void k_head(const float* __restrict__ g,
                                             const float* __restrict__ W1,
                                             const float* __restrict__ W2,
                                             const float* __restrict__ b,
                                             float* __restrict__ out) {
  int gi = blockIdx.x;
  int j = threadIdx.x;
  __shared__ float sg[128];
  sg[j] = g[(size_t)gi * 128 + j];
  sg[j + 64] = g[(size_t)gi * 128 + 64 + j];
  __syncthreads();
  float acc = 0.f;
#pragma unroll
  for (int k = 0; k < 128; ++k) acc = fmaf(sg[k], W1[k * 64 + j], acc);
  acc = fmaxf(acc, 0.f) * W2[j];
#pragma unroll
  for (int off = 32; off > 0; off >>= 1) acc += __shfl_down(acc, off);
  if (j == 0) out[gi] = acc + b[0];
}

extern "C" void kernel_launch(void* const* d_in, const int* in_sizes, int n_in,
                              void* d_out, int out_size, void* d_ws, size_t ws_size,
                              hipStream_t stream) {
  const float* x    = (const float*)d_in[0];
  const float* Wemb = (const float*)d_in[1];
  const float* Wg0  = (const float*)d_in[2];
  const float* Wg1  = (const float*)d_in[3];
  const float* Wg2  = (const float*)d_in[4];
  const float* Wp1  = (const float*)d_in[5];
  const float* Wp2  = (const float*)d_in[6];
  const float* bp2  = (const float*)d_in[7];
  const int* esrc   = (const int*)d_in[8];
  const int* edst   = (const int*)d_in[9];
  const int* gids   = (const int*)d_in[10];
  int N = in_sizes[0] / 35;
  int E = in_sizes[8];
  float* out = (float*)d_out;

  // workspace layout (bytes)
  char* wp = (char*)d_ws;
  float* h0 = (float*)wp;            wp += (size_t)N * 8 * sizeof(float);
  __half* P = (__half*)wp;           wp += (size_t)N * 128 * sizeof(__half);
  __half* Q = (__half*)wp;           wp += (size_t)N * 128 * sizeof(__half);
  float* G  = (float*)wp;            wp += (size_t)NUM_GRAPHS * 128 * sizeof(float);
  int* counts   = (int*)wp;          wp += (size_t)N * sizeof(int);
  int* offs     = (int*)wp;          wp += (size_t)N * sizeof(int);
  int* cursor   = (int*)wp;          wp += (size_t)N * sizeof(int);
  int* partials = (int*)wp;          wp += 512 * sizeof(int);
  int* csr      = (int*)wp;

  int nbE = (E + 255) / 256;
  int nbN = (N + 255) / 256;

  // embed (independent)
  k_embed<<<(N + 31) / 32, 256, 0, stream>>>(x, Wemb, h0, N);

  // CSR build
  hipMemsetAsync(counts, 0, (size_t)N * sizeof(int), stream);
  k_hist<<<nbE, 256, 0, stream>>>(edst, counts, E);
  k_scan1<<<nbN, 256, 0, stream>>>(counts, offs, partials, N);
  k_scan2<<<1, 512, 0, stream>>>(partials, nbN);
  k_scan3<<<nbN, 256, 0, stream>>>(offs, partials, cursor, N);
  k_fill<<<nbE, 256, 0, stream>>>(esrc, edst, cursor, csr, E);

  // zero pooled output (layer-2 epilogue atomics accumulate into it)
  hipMemsetAsync(G, 0, (size_t)NUM_GRAPHS * 128 * sizeof(float), stream);

  // layer 0: P = relu(gather(h0) @ W_g0)   (fp16 out)
  k_layer0<<<(N + 31) / 32, 256, 0, stream>>>(h0, csr, offs, counts, Wg0, P, N);

  // layer 1: Q = relu(gather(P) @ W_g1) + P
  k_gcn_fused<<<(N + 63) / 64, 256, 0, stream>>>(P, csr, offs, counts, Wg1, Q,
                                                 nullptr, nullptr, N, E, 0);

  // layer 2 + pool: G[gid] += relu(gather(Q) @ W_g2) + Q
  k_gcn_fused<<<(N + 63) / 64, 256, 0, stream>>>(Q, csr, offs, counts, Wg2, nullptr,
                                                 G, gids, N, E, 1);

  // head
  k_head<<<NUM_GRAPHS, 64, 0, stream>>>(G, Wp1, Wp2, bp2, out);
}

// Round 9
// 166.830 us; speedup vs baseline: 2.1640x; 1.5035x over previous
//
#include <hip/hip_runtime.h>

// GCNPredictor: 3-layer GCN (sum-aggregation) + sum-pool + MLP head.
// Round 9: R8 gather (best measured) + MFMA GEMM (16x16x32_f16) on an fp16
// LDS agg tile; W_g1/W_g2 pre-transposed to fp16 by k_prepw. Epilogue
// round-trips C through LDS for coalesced residual+store/pool.

constexpr int NUM_GRAPHS = 2048;

typedef _Float16 f16x8 __attribute__((ext_vector_type(8)));
typedef float f32x4 __attribute__((ext_vector_type(4)));

// ---------------- h0 = x @ W_emb  ([N,35] @ [35,8]) ----------------
__global__ __launch_bounds__(256) void k_embed(const float* __restrict__ x,
                                               const float* __restrict__ Wemb,
                                               float* __restrict__ h0, int N) {
  __shared__ float sx[32 * 35];
  __shared__ float sw[35 * 8];
  int n0 = blockIdx.x * 32;
  int cnt = min(32, N - n0);
  int nf = cnt * 35;
  for (int i = threadIdx.x; i < nf; i += 256) sx[i] = x[(size_t)n0 * 35 + i];
  for (int i = threadIdx.x; i < 35 * 8; i += 256) sw[i] = Wemb[i];
  __syncthreads();
  int nl = threadIdx.x >> 3;
  int c = threadIdx.x & 7;
  if (nl < cnt) {
    float acc = 0.f;
#pragma unroll
    for (int k = 0; k < 35; ++k) acc = fmaf(sx[nl * 35 + k], sw[k * 8 + c], acc);
    h0[(size_t)(n0 + nl) * 8 + c] = acc;
  }
}

// ---------------- CSR build: counts -> exclusive scan -> fill ----------------
__global__ __launch_bounds__(256) void k_hist(const int* __restrict__ dst,
                                              int* counts, int E) {
  int e = blockIdx.x * 256 + threadIdx.x;
  if (e < E) atomicAdd(&counts[dst[e]], 1);
}

__global__ __launch_bounds__(256) void k_scan1(const int* __restrict__ counts,
                                               int* __restrict__ offs,
                                               int* __restrict__ partials, int N) {
  __shared__ int s[256];
  int i = blockIdx.x * 256 + threadIdx.x;
  int v = (i < N) ? counts[i] : 0;
  s[threadIdx.x] = v;
  __syncthreads();
#pragma unroll
  for (int d = 1; d < 256; d <<= 1) {
    int t = (threadIdx.x >= d) ? s[threadIdx.x - d] : 0;
    __syncthreads();
    s[threadIdx.x] += t;
    __syncthreads();
  }
  if (i < N) offs[i] = s[threadIdx.x] - v;  // exclusive
  if (threadIdx.x == 255) partials[blockIdx.x] = s[255];
}

__global__ __launch_bounds__(512) void k_scan2(int* partials, int nb) {
  __shared__ int s[512];
  int t = threadIdx.x;
  int orig = (t < nb) ? partials[t] : 0;
  s[t] = orig;
  __syncthreads();
#pragma unroll
  for (int d = 1; d < 512; d <<= 1) {
    int v = (t >= d) ? s[t - d] : 0;
    __syncthreads();
    s[t] += v;
    __syncthreads();
  }
  if (t < nb) partials[t] = s[t] - orig;  // exclusive block offsets
}

__global__ __launch_bounds__(256) void k_scan3(int* __restrict__ offs,
                                               const int* __restrict__ partials,
                                               int* __restrict__ cursor, int N) {
  int i = blockIdx.x * 256 + threadIdx.x;
  if (i < N) {
    int v = offs[i] + partials[blockIdx.x];
    offs[i] = v;
    cursor[i] = v;
  }
}

__global__ __launch_bounds__(256) void k_fill(const int* __restrict__ src,
                                              const int* __restrict__ dst,
                                              int* cursor, int* __restrict__ csr,
                                              int E) {
  int e = blockIdx.x * 256 + threadIdx.x;
  if (e < E) {
    int slot = atomicAdd(&cursor[dst[e]], 1);
    csr[slot] = src[e];
  }
}

// ---- W transpose + fp16 cast: WT[n][k] = W[k][n], 128x128, two matrices ----
__global__ __launch_bounds__(128) void k_prepw(const float* __restrict__ W1,
                                               const float* __restrict__ W2,
                                               _Float16* __restrict__ WT1,
                                               _Float16* __restrict__ WT2) {
  int n = blockIdx.x & 127;
  const float* W = (blockIdx.x < 128) ? W1 : W2;
  _Float16* WT = (blockIdx.x < 128) ? WT1 : WT2;
  int k = threadIdx.x;
  WT[(size_t)n * 128 + k] = (_Float16)W[(size_t)k * 128 + n];
}

// -------- layer 0 fused: agg8 = gather(h0); out = relu(agg8 @ W_g0), fp16 out
__global__ __launch_bounds__(256) void k_layer0(const float* __restrict__ h0,
                                                const int* __restrict__ csr,
                                                const int* __restrict__ offs,
                                                const int* __restrict__ cnts,
                                                const float* __restrict__ W,
                                                _Float16* __restrict__ out, int N) {
  __shared__ float sagg[32 * 9];  // stride 9: conflict-free
  __shared__ float sw[8 * 128];
  for (int i = threadIdx.x; i < 1024; i += 256) sw[i] = W[i];
  int n0 = blockIdx.x * 32;
  {
    int i = threadIdx.x >> 3;
    int c = threadIdx.x & 7;
    int n = n0 + i;
    float acc = 0.f;
    if (n < N) {
      int s = offs[n], cc = cnts[n];
      for (int e = 0; e < cc; ++e) acc += h0[(size_t)csr[s + e] * 8 + c];
    }
    sagg[i * 9 + c] = acc;
  }
  __syncthreads();
  int i2 = threadIdx.x >> 3;
  int j0 = (threadIdx.x & 7) * 16;
  int n2 = n0 + i2;
  if (n2 >= N) return;
  float a[8];
#pragma unroll
  for (int k = 0; k < 8; ++k) a[k] = sagg[i2 * 9 + k];
  float og[16];
#pragma unroll
  for (int j = 0; j < 16; ++j) og[j] = 0.f;
#pragma unroll
  for (int k = 0; k < 8; ++k)
#pragma unroll
    for (int j = 0; j < 16; ++j) og[j] = fmaf(a[k], sw[k * 128 + j0 + j], og[j]);
  size_t base = (size_t)n2 * 128 + j0;
  f16x8 o0, o1;
#pragma unroll
  for (int j = 0; j < 8; ++j) {
    o0[j] = (_Float16)fmaxf(og[j], 0.f);
    o1[j] = (_Float16)fmaxf(og[8 + j], 0.f);
  }
  *reinterpret_cast<f16x8*>(out + base) = o0;
  *reinterpret_cast<f16x8*>(out + base + 8) = o1;
}

// accumulate 8 halves into two float4 accumulators
__device__ __forceinline__ void acc_f16x8(float4& a0, float4& a1, const f16x8 h) {
  a0.x += (float)h[0]; a0.y += (float)h[1]; a0.z += (float)h[2]; a0.w += (float)h[3];
  a1.x += (float)h[4]; a1.y += (float)h[5]; a1.z += (float)h[6]; a1.w += (float)h[7];
}

// -------- fused GCN layer (d=128, fp16 H): agg = gather(H); v = relu(agg@W)+H
// Gather: wave q owns cols [32q,32q+32); lane l owns node n0+l; LDS-staged CSR
// slice; 4-edge unroll. GEMM: MFMA 16x16x32_f16 on fp16 LDS tile; WT = W^T fp16.
// mode 0: out[n] = v (fp16). mode 1: G[gid[n]] += v (pool fused, fp32 G).
__global__ __launch_bounds__(256, 4) void k_gcn_fused(
    const _Float16* __restrict__ H, const int* __restrict__ csr,
    const int* __restrict__ offs, const int* __restrict__ cnts,
    const _Float16* __restrict__ WT, _Float16* __restrict__ out,
    float* G, const int* __restrict__ gid, int N, int E, int mode) {
  __shared__ _Float16 sa_h[64 * 136];  // padded: row stride 272 B
  int* sidx = reinterpret_cast<int*>(sa_h);  // aliased during gather
  int n0 = blockIdx.x * 64;

  int e0 = offs[n0];
  int e1 = (n0 + 64 < N) ? offs[n0 + 64] : E;
  int nedge = e1 - e0;
  bool staged = (nedge <= 64 * 136 / 2);

  if (staged) {
    for (int i = threadIdx.x; i < nedge; i += 256) sidx[i] = csr[e0 + i];
  }
  __syncthreads();

  // ---- gather phase (fp32 acc in regs) ----
  int q = threadIdx.x >> 6;  // column quarter
  int l = threadIdx.x & 63;  // node lane
  {
    int n = n0 + l;
    float4 acc[8];
#pragma unroll
    for (int i = 0; i < 8; ++i) acc[i] = make_float4(0.f, 0.f, 0.f, 0.f);
    int cnt = (n < N) ? cnts[n] : 0;
    int sb = (n < N) ? (offs[n] - e0) : 0;
    const _Float16* Hq = H + q * 32;
    if (staged) {
      int e = 0;
      for (; e + 4 <= cnt; e += 4) {
        int s0 = sidx[sb + e], s1 = sidx[sb + e + 1];
        int s2 = sidx[sb + e + 2], s3 = sidx[sb + e + 3];
        const f16x8* r0 = reinterpret_cast<const f16x8*>(Hq + (size_t)s0 * 128);
        const f16x8* r1 = reinterpret_cast<const f16x8*>(Hq + (size_t)s1 * 128);
        const f16x8* r2 = reinterpret_cast<const f16x8*>(Hq + (size_t)s2 * 128);
        const f16x8* r3 = reinterpret_cast<const f16x8*>(Hq + (size_t)s3 * 128);
        f16x8 a0 = r0[0], a1 = r0[1], a2 = r0[2], a3 = r0[3];
        f16x8 b0 = r1[0], b1 = r1[1], b2 = r1[2], b3 = r1[3];
        f16x8 c0 = r2[0], c1 = r2[1], c2 = r2[2], c3 = r2[3];
        f16x8 d0 = r3[0], d1 = r3[1], d2 = r3[2], d3 = r3[3];
        acc_f16x8(acc[0], acc[1], a0); acc_f16x8(acc[2], acc[3], a1);
        acc_f16x8(acc[4], acc[5], a2); acc_f16x8(acc[6], acc[7], a3);
        acc_f16x8(acc[0], acc[1], b0); acc_f16x8(acc[2], acc[3], b1);
        acc_f16x8(acc[4], acc[5], b2); acc_f16x8(acc[6], acc[7], b3);
        acc_f16x8(acc[0], acc[1], c0); acc_f16x8(acc[2], acc[3], c1);
        acc_f16x8(acc[4], acc[5], c2); acc_f16x8(acc[6], acc[7], c3);
        acc_f16x8(acc[0], acc[1], d0); acc_f16x8(acc[2], acc[3], d1);
        acc_f16x8(acc[4], acc[5], d2); acc_f16x8(acc[6], acc[7], d3);
      }
      for (; e < cnt; ++e) {
        int s0 = sidx[sb + e];
        const f16x8* r0 = reinterpret_cast<const f16x8*>(Hq + (size_t)s0 * 128);
        f16x8 a0 = r0[0], a1 = r0[1], a2 = r0[2], a3 = r0[3];
        acc_f16x8(acc[0], acc[1], a0); acc_f16x8(acc[2], acc[3], a1);
        acc_f16x8(acc[4], acc[5], a2); acc_f16x8(acc[6], acc[7], a3);
      }
    } else {
      int s = (n < N) ? offs[n] : 0;
      for (int e = 0; e < cnt; ++e) {
        int s0 = csr[s + e];
        const f16x8* r0 = reinterpret_cast<const f16x8*>(Hq + (size_t)s0 * 128);
        f16x8 a0 = r0[0], a1 = r0[1], a2 = r0[2], a3 = r0[3];
        acc_f16x8(acc[0], acc[1], a0); acc_f16x8(acc[2], acc[3], a1);
        acc_f16x8(acc[4], acc[5], a2); acc_f16x8(acc[6], acc[7], a3);
      }
    }
    __syncthreads();  // all sidx reads done; sa_h can be overwritten
    // store agg as fp16 (A-tile for MFMA)
    float* af = reinterpret_cast<float*>(acc);
#pragma unroll
    for (int j = 0; j < 4; ++j) {
      f16x8 st;
#pragma unroll
      for (int i = 0; i < 8; ++i) st[i] = (_Float16)af[j * 8 + i];
      *reinterpret_cast<f16x8*>(&sa_h[l * 136 + q * 32 + j * 8]) = st;
    }
  }
  __syncthreads();

  // ---- MFMA GEMM: C[64][128] = sa_h[64][128] @ W ; wave w -> cols [32w,32w+32)
  {
    int w = threadIdx.x >> 6;
    int lane = threadIdx.x & 63;
    int lr = lane & 15;
    int lg = lane >> 4;
    f32x4 C[4][2];
#pragma unroll
    for (int mt = 0; mt < 4; ++mt)
#pragma unroll
      for (int nt = 0; nt < 2; ++nt) C[mt][nt] = (f32x4){0.f, 0.f, 0.f, 0.f};
    const _Float16* WTb = WT + (size_t)(w * 32) * 128;
#pragma unroll
    for (int kk = 0; kk < 4; ++kk) {
      int k0 = kk * 32 + lg * 8;
      f16x8 a0 = *reinterpret_cast<const f16x8*>(&sa_h[(0 + lr) * 136 + k0]);
      f16x8 a1 = *reinterpret_cast<const f16x8*>(&sa_h[(16 + lr) * 136 + k0]);
      f16x8 a2 = *reinterpret_cast<const f16x8*>(&sa_h[(32 + lr) * 136 + k0]);
      f16x8 a3 = *reinterpret_cast<const f16x8*>(&sa_h[(48 + lr) * 136 + k0]);
      f16x8 b0 = *reinterpret_cast<const f16x8*>(&WTb[(size_t)lr * 128 + k0]);
      f16x8 b1 = *reinterpret_cast<const f16x8*>(&WTb[(size_t)(16 + lr) * 128 + k0]);
      C[0][0] = __builtin_amdgcn_mfma_f32_16x16x32_f16(a0, b0, C[0][0], 0, 0, 0);
      C[1][0] = __builtin_amdgcn_mfma_f32_16x16x32_f16(a1, b0, C[1][0], 0, 0, 0);
      C[2][0] = __builtin_amdgcn_mfma_f32_16x16x32_f16(a2, b0, C[2][0], 0, 0, 0);
      C[3][0] = __builtin_amdgcn_mfma_f32_16x16x32_f16(a3, b0, C[3][0], 0, 0, 0);
      C[0][1] = __builtin_amdgcn_mfma_f32_16x16x32_f16(a0, b1, C[0][1], 0, 0, 0);
      C[1][1] = __builtin_amdgcn_mfma_f32_16x16x32_f16(a1, b1, C[1][1], 0, 0, 0);
      C[2][1] = __builtin_amdgcn_mfma_f32_16x16x32_f16(a2, b1, C[2][1], 0, 0, 0);
      C[3][1] = __builtin_amdgcn_mfma_f32_16x16x32_f16(a3, b1, C[3][1], 0, 0, 0);
    }
    __syncthreads();  // all A reads complete before overwrite
    // write relu(C) back to sa_h (C/D layout: col=lane&15, row=(lane>>4)*4+r)
#pragma unroll
    for (int mt = 0; mt < 4; ++mt)
#pragma unroll
      for (int nt = 0; nt < 2; ++nt)
#pragma unroll
        for (int r = 0; r < 4; ++r) {
          int row = mt * 16 + lg * 4 + r;
          int col = w * 32 + nt * 16 + lr;
          sa_h[row * 136 + col] = (_Float16)fmaxf(C[mt][nt][r], 0.f);
        }
  }
  __syncthreads();

  // ---- epilogue: v = relu(C) + H (residual); store or pool ----
  int nl = threadIdx.x >> 4;
  int j0 = (threadIdx.x & 15) * 8;
  if (mode == 0) {
#pragma unroll
    for (int r = 0; r < 4; ++r) {
      int row = nl + 16 * r;
      int n = n0 + row;
      if (n < N) {
        size_t base = (size_t)n * 128 + j0;
        f16x8 vv = *reinterpret_cast<const f16x8*>(&sa_h[row * 136 + j0]);
        f16x8 hh = *reinterpret_cast<const f16x8*>(H + base);
        f16x8 o;
#pragma unroll
        for (int i = 0; i < 8; ++i) o[i] = (_Float16)((float)vv[i] + (float)hh[i]);
        *reinterpret_cast<f16x8*>(out + base) = o;
      }
    }
  } else {
#pragma unroll
    for (int r = 0; r < 4; ++r) {
      int row = nl + 16 * r;
      int n = n0 + row;
      if (n < N) {
        size_t base = (size_t)n * 128 + j0;
        f16x8 vv = *reinterpret_cast<const f16x8*>(&sa_h[row * 136 + j0]);
        f16x8 hh = *reinterpret_cast<const f16x8*>(H + base);
        f16x8 o;
#pragma unroll
        for (int i = 0; i < 8; ++i) o[i] = (_Float16)((float)vv[i] + (float)hh[i]);
        *reinterpret_cast<f16x8*>(&sa_h[row * 136 + j0]) = o;
      }
    }
    __syncthreads();
    int grp = threadIdx.x >> 7;  // 0..1 -> rows [0,32) / [32,64)
    int j = threadIdx.x & 127;
    int r0 = grp * 32;
    int nfirst = n0 + r0;
    if (nfirst < N) {
      float pacc = 0.f;
      int cur = gid[nfirst];
      for (int r = r0; r < r0 + 32; ++r) {
        int n = n0 + r;
        if (n >= N) break;
        int g2 = gid[n];
        if (g2 != cur) {
          atomicAdd(&G[(size_t)cur * 128 + j], pacc);
          pacc = 0.f;
          cur = g2;
        }
        pacc += (float)sa_h[r * 136 + j];
      }
      atomicAdd(&G[(size_t)cur * 128 + j], pacc);
    }
  }
}

// ---------------- pred = relu(g @ W_p1) @ W_p2 + b ----------------
__global__ __launch_bounds__(64) void k_head(const float* __restrict__ g,
                                             const float* __restrict__ W1,
                                             const float* __restrict__ W2,
                                             const float* __restrict__ b,
                                             float* __restrict__ out) {
  int gi = blockIdx.x;
  int j = threadIdx.x;
  __shared__ float sg[128];
  sg[j] = g[(size_t)gi * 128 + j];
  sg[j + 64] = g[(size_t)gi * 128 + 64 + j];
  __syncthreads();
  float acc = 0.f;
#pragma unroll
  for (int k = 0; k < 128; ++k) acc = fmaf(sg[k], W1[k * 64 + j], acc);
  acc = fmaxf(acc, 0.f) * W2[j];
#pragma unroll
  for (int off = 32; off > 0; off >>= 1) acc += __shfl_down(acc, off);
  if (j == 0) out[gi] = acc + b[0];
}

extern "C" void kernel_launch(void* const* d_in, const int* in_sizes, int n_in,
                              void* d_out, int out_size, void* d_ws, size_t ws_size,
                              hipStream_t stream) {
  const float* x    = (const float*)d_in[0];
  const float* Wemb = (const float*)d_in[1];
  const float* Wg0  = (const float*)d_in[2];
  const float* Wg1  = (const float*)d_in[3];
  const float* Wg2  = (const float*)d_in[4];
  const float* Wp1  = (const float*)d_in[5];
  const float* Wp2  = (const float*)d_in[6];
  const float* bp2  = (const float*)d_in[7];
  const int* esrc   = (const int*)d_in[8];
  const int* edst   = (const int*)d_in[9];
  const int* gids   = (const int*)d_in[10];
  int N = in_sizes[0] / 35;
  int E = in_sizes[8];
  float* out = (float*)d_out;

  // workspace layout (bytes)
  char* wp = (char*)d_ws;
  float* h0 = (float*)wp;            wp += (size_t)N * 8 * sizeof(float);
  _Float16* P = (_Float16*)wp;       wp += (size_t)N * 128 * sizeof(_Float16);
  _Float16* Q = (_Float16*)wp;       wp += (size_t)N * 128 * sizeof(_Float16);
  float* G  = (float*)wp;            wp += (size_t)NUM_GRAPHS * 128 * sizeof(float);
  int* counts   = (int*)wp;          wp += (size_t)N * sizeof(int);
  int* offs     = (int*)wp;          wp += (size_t)N * sizeof(int);
  int* cursor   = (int*)wp;          wp += (size_t)N * sizeof(int);
  int* partials = (int*)wp;          wp += 512 * sizeof(int);
  int* csr      = (int*)wp;          wp += (size_t)E * sizeof(int);
  _Float16* WT1 = (_Float16*)wp;     wp += (size_t)128 * 128 * sizeof(_Float16);
  _Float16* WT2 = (_Float16*)wp;

  int nbE = (E + 255) / 256;
  int nbN = (N + 255) / 256;

  // embed + weight prep (independent)
  k_embed<<<(N + 31) / 32, 256, 0, stream>>>(x, Wemb, h0, N);
  k_prepw<<<256, 128, 0, stream>>>(Wg1, Wg2, WT1, WT2);

  // CSR build
  hipMemsetAsync(counts, 0, (size_t)N * sizeof(int), stream);
  k_hist<<<nbE, 256, 0, stream>>>(edst, counts, E);
  k_scan1<<<nbN, 256, 0, stream>>>(counts, offs, partials, N);
  k_scan2<<<1, 512, 0, stream>>>(partials, nbN);
  k_scan3<<<nbN, 256, 0, stream>>>(offs, partials, cursor, N);
  k_fill<<<nbE, 256, 0, stream>>>(esrc, edst, cursor, csr, E);

  // zero pooled output (layer-2 epilogue atomics accumulate into it)
  hipMemsetAsync(G, 0, (size_t)NUM_GRAPHS * 128 * sizeof(float), stream);

  // layer 0: P = relu(gather(h0) @ W_g0)   (fp16 out)
  k_layer0<<<(N + 31) / 32, 256, 0, stream>>>(h0, csr, offs, counts, Wg0, P, N);

  // layer 1: Q = relu(gather(P) @ W_g1) + P
  k_gcn_fused<<<(N + 63) / 64, 256, 0, stream>>>(P, csr, offs, counts, WT1, Q,
                                                 nullptr, nullptr, N, E, 0);

  // layer 2 + pool: G[gid] += relu(gather(Q) @ W_g2) + Q
  k_gcn_fused<<<(N + 63) / 64, 256, 0, stream>>>(Q, csr, offs, counts, WT2, nullptr,
                                                 G, gids, N, E, 1);

  // head
  k_head<<<NUM_GRAPHS, 64, 0, stream>>>(G, Wp1, Wp2, bp2, out);
}